// Round 2
// baseline (2975.088 us; speedup 1.0000x reference)
//
#include <hip/hip_runtime.h>

// Match numpy f32 semantics: no FMA contraction anywhere in this TU.
#pragma clang fp contract(off)

#define VWD 96
#define NVERT 2048
#define NFAC 512
#define NBATCH 8

// Monotonic float->uint key: unsigned compare order == float order.
__device__ __forceinline__ unsigned fkey(float f) {
    unsigned u = __float_as_uint(f);
    return (u & 0x80000000u) ? ~u : (u | 0x80000000u);
}

// ---------------------------------------------------------------------------
// Kernel 1: per-batch facet precompute into d_ws, sorted by |det| descending
// (output is an OR over facets -> order-independent; big tets hit first).
//   bbk[b][s][8]  : monotonic-uint bbox keys (minx,miny,minz,maxx,maxy,maxz,0,0)
//   body[b][s][16]: det, v3x, v3y, v3z, A00..A22, pad
// ---------------------------------------------------------------------------
__global__ __launch_bounds__(256) void precompute_kernel(
    const float* __restrict__ vertices,
    const int*   __restrict__ facets,
    unsigned*    __restrict__ bbk,
    float*       __restrict__ body)
{
    __shared__ unsigned skey[NFAC];
    __shared__ int      sidx[NFAC];
    const int b   = blockIdx.x;
    const int tid = threadIdx.x;
    const float* vb = vertices + (size_t)b * NVERT * 3;

    // pass 1: |det| sort keys
    for (int j = tid; j < NFAC; j += 256) {
        int4 fi = ((const int4*)facets)[b * NFAC + j];
        float x0 = vb[3*fi.x+0], y0 = vb[3*fi.x+1], z0 = vb[3*fi.x+2];
        float x1 = vb[3*fi.y+0], y1 = vb[3*fi.y+1], z1 = vb[3*fi.y+2];
        float x2 = vb[3*fi.z+0], y2 = vb[3*fi.z+1], z2 = vb[3*fi.z+2];
        float x3 = vb[3*fi.w+0], y3 = vb[3*fi.w+1], z3 = vb[3*fi.w+2];
        float a  = x0-x3, bb = x1-x3, c  = x2-x3;
        float d  = y0-y3, e  = y1-y3, f  = y2-y3;
        float g  = z0-z3, h  = z1-z3, ii = z2-z3;
        float det = a*(e*ii - f*h) - bb*(d*ii - f*g) + c*(d*h - e*g);
        skey[j] = ~__float_as_uint(fabsf(det));  // ascending key == descending |det|
        sidx[j] = j;
    }
    __syncthreads();

    // bitonic sort (ascending in skey)
    for (unsigned k = 2; k <= NFAC; k <<= 1) {
        for (unsigned j = k >> 1; j > 0; j >>= 1) {
            for (int t = tid; t < NFAC; t += 256) {
                int partner = t ^ (int)j;
                if (partner > t) {
                    bool up = ((t & k) == 0);
                    unsigned ka = skey[t], kb2 = skey[partner];
                    if ((ka > kb2) == up) {
                        skey[t] = kb2; skey[partner] = ka;
                        int ia = sidx[t]; sidx[t] = sidx[partner]; sidx[partner] = ia;
                    }
                }
            }
            __syncthreads();
        }
    }

    // pass 2: full per-facet data written in sorted order
    for (int s = tid; s < NFAC; s += 256) {
        int j = sidx[s];
        int4 fi = ((const int4*)facets)[b * NFAC + j];
        float x0 = vb[3*fi.x+0], y0 = vb[3*fi.x+1], z0 = vb[3*fi.x+2];
        float x1 = vb[3*fi.y+0], y1 = vb[3*fi.y+1], z1 = vb[3*fi.y+2];
        float x2 = vb[3*fi.z+0], y2 = vb[3*fi.z+1], z2 = vb[3*fi.z+2];
        float x3 = vb[3*fi.w+0], y3 = vb[3*fi.w+1], z3 = vb[3*fi.w+2];
        float a  = x0-x3, bb = x1-x3, c  = x2-x3;
        float d  = y0-y3, e  = y1-y3, f  = y2-y3;
        float g  = z0-z3, h  = z1-z3, ii = z2-z3;
        float A00 = e*ii - f*h,  A01 = c*h  - bb*ii, A02 = bb*f - c*e;
        float A10 = f*g  - d*ii, A11 = a*ii - c*g,   A12 = c*d  - a*f;
        float A20 = d*h  - e*g,  A21 = bb*g - a*h,   A22 = a*e  - bb*d;
        float det = a*(e*ii - f*h) - bb*(d*ii - f*g) + c*(d*h - e*g);
        float bminx = fminf(fminf(x0,x1),fminf(x2,x3)) - 1e-4f;
        float bminy = fminf(fminf(y0,y1),fminf(y2,y3)) - 1e-4f;
        float bminz = fminf(fminf(z0,z1),fminf(z2,z3)) - 1e-4f;
        float bmaxx = fmaxf(fmaxf(x0,x1),fmaxf(x2,x3)) + 1e-4f;
        float bmaxy = fmaxf(fmaxf(y0,y1),fmaxf(y2,y3)) + 1e-4f;
        float bmaxz = fmaxf(fmaxf(z0,z1),fmaxf(z2,z3)) + 1e-4f;
        unsigned* bk = bbk + ((size_t)b * NFAC + s) * 8;
        bk[0] = fkey(bminx); bk[1] = fkey(bminy); bk[2] = fkey(bminz);
        bk[3] = fkey(bmaxx); bk[4] = fkey(bmaxy); bk[5] = fkey(bmaxz);
        bk[6] = 0u;          bk[7] = 0u;
        float* bo = body + ((size_t)b * NFAC + s) * 16;
        bo[0]  = det; bo[1]  = x3;  bo[2]  = y3;  bo[3]  = z3;
        bo[4]  = A00; bo[5]  = A01; bo[6]  = A02;
        bo[7]  = A10; bo[8]  = A11; bo[9]  = A12;
        bo[10] = A20; bo[11] = A21; bo[12] = A22;
        bo[13] = 0.0f; bo[14] = 0.0f; bo[15] = 0.0f;
    }
}

// ---------------------------------------------------------------------------
// Kernel 2: one wave per 4x4x4 voxel cube. Facet data read via wave-uniform
// (scalar-cache) loads; bbox reject on SALU via monotonic-int keys; early
// exit when all 64 lanes have found a covering tet.
// ---------------------------------------------------------------------------
__global__ __launch_bounds__(256) void voxelize_kernel(
    const unsigned* __restrict__ bbk,
    const float*    __restrict__ body,
    float*          __restrict__ out)
{
    const int b    = blockIdx.y;
    const int wave = threadIdx.x >> 6;
    const int lane = threadIdx.x & 63;
    const int cube = blockIdx.x * 4 + wave;          // 0 .. 13823
    const int cz  = cube % 24;
    const int cyx = cube / 24;
    const int cy  = cyx % 24;
    const int cx  = cyx / 24;
    const int iz = cz*4 + (lane & 3);
    const int iy = cy*4 + ((lane >> 2) & 3);
    const int ix = cx*4 + (lane >> 4);

    // grid point (exact-numerator, correctly-rounded division == jnp f32)
    const float px = (float)(2*ix + 1 - VWD) / 96.0f;
    const float py = (float)(2*iy + 1 - VWD) / 96.0f;
    const float pz = (float)(2*iz + 1 - VWD) / 96.0f;

    // wave-uniform cube bounds as monotonic keys, forced into SGPRs
    const unsigned ckMinX = (unsigned)__builtin_amdgcn_readfirstlane(
        (int)fkey((float)(2*(cx*4)   + 1 - VWD) / 96.0f));
    const unsigned ckMaxX = (unsigned)__builtin_amdgcn_readfirstlane(
        (int)fkey((float)(2*(cx*4+3) + 1 - VWD) / 96.0f));
    const unsigned ckMinY = (unsigned)__builtin_amdgcn_readfirstlane(
        (int)fkey((float)(2*(cy*4)   + 1 - VWD) / 96.0f));
    const unsigned ckMaxY = (unsigned)__builtin_amdgcn_readfirstlane(
        (int)fkey((float)(2*(cy*4+3) + 1 - VWD) / 96.0f));
    const unsigned ckMinZ = (unsigned)__builtin_amdgcn_readfirstlane(
        (int)fkey((float)(2*(cz*4)   + 1 - VWD) / 96.0f));
    const unsigned ckMaxZ = (unsigned)__builtin_amdgcn_readfirstlane(
        (int)fkey((float)(2*(cz*4+3) + 1 - VWD) / 96.0f));

    const unsigned* kb = bbk  + (size_t)b * NFAC * 8;
    const float4*   bo = (const float4*)(body + (size_t)b * NFAC * 16);

    bool found = false;
    for (int f = 0; f < NFAC; ++f) {
        unsigned kminx = kb[f*8+0];
        unsigned kminy = kb[f*8+1];
        unsigned kminz = kb[f*8+2];
        unsigned kmaxx = kb[f*8+3];
        unsigned kmaxy = kb[f*8+4];
        unsigned kmaxz = kb[f*8+5];
        // wave-uniform (scalar) bbox reject
        if (ckMaxX < kminx || ckMinX > kmaxx ||
            ckMaxY < kminy || ckMinY > kmaxy ||
            ckMaxZ < kminz || ckMinZ > kmaxz) continue;

        float4 c0 = bo[f*4+0];   // det, v3x, v3y, v3z
        float4 c1 = bo[f*4+1];   // A00, A01, A02, A10
        float4 c2 = bo[f*4+2];   // A11, A12, A20, A21
        float4 c3 = bo[f*4+3];   // A22, -, -, -
        float det = c0.x;
        float dx = px - c0.y;
        float dy = py - c0.z;
        float dz = pz - c0.w;
        // left-assoc dot products, true f32 division (matches ref rounding)
        float n0 = c1.x*dx + c1.y*dy + c1.z*dz;
        float n1 = c1.w*dx + c2.x*dy + c2.y*dz;
        float n2 = c2.z*dx + c2.w*dy + c3.x*dz;
        float l0 = n0 / det;
        float l1 = n1 / det;
        float l2 = n2 / det;
        float l3 = 1.0f - (l0 + l1 + l2);
        bool inside = (l0 >= 0.0f) & (l0 <= 1.0f) &
                      (l1 >= 0.0f) & (l1 <= 1.0f) &
                      (l2 >= 0.0f) & (l2 <= 1.0f) &
                      (l3 >= 0.0f) & (l3 <= 1.0f);
        if (inside) { found = true; break; }
    }

    out[(size_t)b * (VWD*VWD*VWD) + (size_t)ix*(VWD*VWD) + iy*VWD + iz]
        = found ? 1.0f : 0.0f;
}

extern "C" void kernel_launch(void* const* d_in, const int* in_sizes, int n_in,
                              void* d_out, int out_size, void* d_ws, size_t ws_size,
                              hipStream_t stream) {
    const float* vertices = (const float*)d_in[0];   // (8, 2048, 3) f32
    const int*   facets   = (const int*)d_in[1];     // (8, 512, 4) int
    float*       out      = (float*)d_out;           // (8, 96, 96, 96) f32

    // d_ws layout: bbk (8*512*8 u32 = 128 KB) | body (8*512*16 f32 = 256 KB)
    unsigned* bbk  = (unsigned*)d_ws;
    float*    body = (float*)((char*)d_ws + (size_t)NBATCH * NFAC * 8 * 4);

    precompute_kernel<<<NBATCH, 256, 0, stream>>>(vertices, facets, bbk, body);
    dim3 grid(3456, NBATCH);   // 3456 blocks * 4 waves = 13824 cubes per batch
    voxelize_kernel<<<grid, 256, 0, stream>>>(bbk, body, out);
}

// Round 3
// 716.031 us; speedup vs baseline: 4.1550x; 4.1550x over previous
//
#include <hip/hip_runtime.h>

// Match numpy f32 semantics: no FMA contraction anywhere in this TU.
#pragma clang fp contract(off)

#define VWD 96
#define NVERT 2048
#define NFAC 512
#define NBATCH 8
#define NSC 1728   // 12^3 supercells (8x8x8 voxels each)

// ---------------------------------------------------------------------------
// Kernel 1: per-batch facet precompute into d_ws, sorted by |det| descending
// (output is an OR over facets -> order-independent; big tets hit first).
//   fbb[b][s][8]  : f32 bbox (minx,miny,minz,maxx,maxy,maxz,0,0), +-1e-4 margin
//   body[b][s][16]: det, v3x, v3y, v3z, A00..A22, pad
// ---------------------------------------------------------------------------
__global__ __launch_bounds__(256) void precompute_kernel(
    const float* __restrict__ vertices,
    const int*   __restrict__ facets,
    float*       __restrict__ fbb,
    float*       __restrict__ body)
{
    __shared__ unsigned skey[NFAC];
    __shared__ int      sidx[NFAC];
    const int b   = blockIdx.x;
    const int tid = threadIdx.x;
    const float* vb = vertices + (size_t)b * NVERT * 3;

    // pass 1: |det| sort keys
    for (int j = tid; j < NFAC; j += 256) {
        int4 fi = ((const int4*)facets)[b * NFAC + j];
        float x0 = vb[3*fi.x+0], y0 = vb[3*fi.x+1], z0 = vb[3*fi.x+2];
        float x1 = vb[3*fi.y+0], y1 = vb[3*fi.y+1], z1 = vb[3*fi.y+2];
        float x2 = vb[3*fi.z+0], y2 = vb[3*fi.z+1], z2 = vb[3*fi.z+2];
        float x3 = vb[3*fi.w+0], y3 = vb[3*fi.w+1], z3 = vb[3*fi.w+2];
        float a  = x0-x3, bb = x1-x3, c  = x2-x3;
        float d  = y0-y3, e  = y1-y3, f  = y2-y3;
        float g  = z0-z3, h  = z1-z3, ii = z2-z3;
        float det = a*(e*ii - f*h) - bb*(d*ii - f*g) + c*(d*h - e*g);
        skey[j] = ~__float_as_uint(fabsf(det));  // ascending key == descending |det|
        sidx[j] = j;
    }
    __syncthreads();

    // bitonic sort (ascending in skey)
    for (unsigned k = 2; k <= NFAC; k <<= 1) {
        for (unsigned j = k >> 1; j > 0; j >>= 1) {
            for (int t = tid; t < NFAC; t += 256) {
                int partner = t ^ (int)j;
                if (partner > t) {
                    bool up = ((t & k) == 0);
                    unsigned ka = skey[t], kb2 = skey[partner];
                    if ((ka > kb2) == up) {
                        skey[t] = kb2; skey[partner] = ka;
                        int ia = sidx[t]; sidx[t] = sidx[partner]; sidx[partner] = ia;
                    }
                }
            }
            __syncthreads();
        }
    }

    // pass 2: full per-facet data written in sorted order
    for (int s = tid; s < NFAC; s += 256) {
        int j = sidx[s];
        int4 fi = ((const int4*)facets)[b * NFAC + j];
        float x0 = vb[3*fi.x+0], y0 = vb[3*fi.x+1], z0 = vb[3*fi.x+2];
        float x1 = vb[3*fi.y+0], y1 = vb[3*fi.y+1], z1 = vb[3*fi.y+2];
        float x2 = vb[3*fi.z+0], y2 = vb[3*fi.z+1], z2 = vb[3*fi.z+2];
        float x3 = vb[3*fi.w+0], y3 = vb[3*fi.w+1], z3 = vb[3*fi.w+2];
        float a  = x0-x3, bb = x1-x3, c  = x2-x3;
        float d  = y0-y3, e  = y1-y3, f  = y2-y3;
        float g  = z0-z3, h  = z1-z3, ii = z2-z3;
        float A00 = e*ii - f*h,  A01 = c*h  - bb*ii, A02 = bb*f - c*e;
        float A10 = f*g  - d*ii, A11 = a*ii - c*g,   A12 = c*d  - a*f;
        float A20 = d*h  - e*g,  A21 = bb*g - a*h,   A22 = a*e  - bb*d;
        float det = a*(e*ii - f*h) - bb*(d*ii - f*g) + c*(d*h - e*g);
        float bminx = fminf(fminf(x0,x1),fminf(x2,x3)) - 1e-4f;
        float bminy = fminf(fminf(y0,y1),fminf(y2,y3)) - 1e-4f;
        float bminz = fminf(fminf(z0,z1),fminf(z2,z3)) - 1e-4f;
        float bmaxx = fmaxf(fmaxf(x0,x1),fmaxf(x2,x3)) + 1e-4f;
        float bmaxy = fmaxf(fmaxf(y0,y1),fmaxf(y2,y3)) + 1e-4f;
        float bmaxz = fmaxf(fmaxf(z0,z1),fmaxf(z2,z3)) + 1e-4f;
        float* fb = fbb + ((size_t)b * NFAC + s) * 8;
        fb[0] = bminx; fb[1] = bminy; fb[2] = bminz;
        fb[3] = bmaxx; fb[4] = bmaxy; fb[5] = bmaxz;
        fb[6] = 0.0f;  fb[7] = 0.0f;
        float* bo = body + ((size_t)b * NFAC + s) * 16;
        bo[0]  = det; bo[1]  = x3;  bo[2]  = y3;  bo[3]  = z3;
        bo[4]  = A00; bo[5]  = A01; bo[6]  = A02;
        bo[7]  = A10; bo[8]  = A11; bo[9]  = A12;
        bo[10] = A20; bo[11] = A21; bo[12] = A22;
        bo[13] = 0.0f; bo[14] = 0.0f; bo[15] = 0.0f;
    }
}

// ---------------------------------------------------------------------------
// Kernel 2: per-supercell 512-bit facet mask. Block = 512 threads = 8 waves;
// wave w's ballot is mask word w (bit l = facet w*64+l overlaps supercell).
// ---------------------------------------------------------------------------
__global__ __launch_bounds__(512) void mask_kernel(
    const float* __restrict__ fbb,
    unsigned long long* __restrict__ masks)
{
    const int sc = blockIdx.x;    // 0..1727
    const int b  = blockIdx.y;
    const int f  = threadIdx.x;   // facet id (sorted order)
    const float* fb = fbb + ((size_t)b * NFAC + f) * 8;
    float bminx = fb[0], bminy = fb[1], bminz = fb[2];
    float bmaxx = fb[3], bmaxy = fb[4], bmaxz = fb[5];
    const int sz = sc % 12, sy = (sc / 12) % 12, sx = sc / 144;
    // voxel-center bounds of this 8x8x8 supercell
    const float scminx = (float)(16*sx + 1 - VWD) / 96.0f;
    const float scmaxx = (float)(16*sx + 15 - VWD) / 96.0f;
    const float scminy = (float)(16*sy + 1 - VWD) / 96.0f;
    const float scmaxy = (float)(16*sy + 15 - VWD) / 96.0f;
    const float scminz = (float)(16*sz + 1 - VWD) / 96.0f;
    const float scmaxz = (float)(16*sz + 15 - VWD) / 96.0f;
    bool ov = (bminx <= scmaxx) & (bmaxx >= scminx) &
              (bminy <= scmaxy) & (bmaxy >= scminy) &
              (bminz <= scmaxz) & (bmaxz >= scminz);
    unsigned long long bal = __ballot((int)ov);
    if ((threadIdx.x & 63) == 0)
        masks[((size_t)b * NSC + sc) * 8 + (threadIdx.x >> 6)] = bal;
}

// ---------------------------------------------------------------------------
// Kernel 3: one wave per 4x4x4 cube. Candidates come from the supercell's
// bitmask (SALU bit-scan, zero reject iterations); facet body via wave-uniform
// scalar loads; f32 conservative pre-test skips the IEEE division sequences
// unless some lane might be inside; early exit when all 64 lanes found.
// ---------------------------------------------------------------------------
__global__ __launch_bounds__(256) void voxelize_kernel(
    const float*              __restrict__ body,
    const unsigned long long* __restrict__ masks,
    float*                    __restrict__ out)
{
    const int b    = blockIdx.y;
    const int wave = threadIdx.x >> 6;
    const int lane = threadIdx.x & 63;
    const int cube = blockIdx.x * 4 + wave;          // 0 .. 13823
    const int cz  = cube % 24;
    const int cyx = cube / 24;
    const int cy  = cyx % 24;
    const int cx  = cyx / 24;
    const int iz = cz*4 + (lane & 3);
    const int iy = cy*4 + ((lane >> 2) & 3);
    const int ix = cx*4 + (lane >> 4);

    // grid point (exact-numerator, correctly-rounded division == numpy f32)
    const float px = (float)(2*ix + 1 - VWD) / 96.0f;
    const float py = (float)(2*iy + 1 - VWD) / 96.0f;
    const float pz = (float)(2*iz + 1 - VWD) / 96.0f;

    const int scid = __builtin_amdgcn_readfirstlane(
        (cx >> 1) * 144 + (cy >> 1) * 12 + (cz >> 1));
    const unsigned long long* mp = masks + ((size_t)b * NSC + scid) * 8;
    const float* bb = body + (size_t)b * NFAC * 16;

    bool found = false;
    for (int w = 0; w < 8; ++w) {
        unsigned long long m = mp[w];   // wave-uniform -> SGPR
        while (m) {
            int bit = __builtin_ctzll(m);
            m &= m - 1;
            int f = __builtin_amdgcn_readfirstlane(w * 64 + bit);
            const float* bo = bb + f * 16;
            float det = bo[0], v3x = bo[1], v3y = bo[2], v3z = bo[3];
            float A00 = bo[4],  A01 = bo[5],  A02 = bo[6];
            float A10 = bo[7],  A11 = bo[8],  A12 = bo[9];
            float A20 = bo[10], A21 = bo[11], A22 = bo[12];
            float dx = px - v3x, dy = py - v3y, dz = pz - v3z;
            // left-assoc dot products (matches ref)
            float n0 = A00*dx + A01*dy + A02*dz;
            float n1 = A10*dx + A11*dy + A12*dz;
            float n2 = A20*dx + A21*dy + A22*dz;
            // conservative pre-test: ref-inside => maybe (1e-4 rel margin
            // dwarfs the ~1e-7 rel slop of rounded-quotient membership)
            float adet = fabsf(det);
            float sd   = (det < 0.0f) ? -1.0f : 1.0f;
            float m0 = n0*sd, m1 = n1*sd, m2 = n2*sd;
            float marg = adet * 1e-4f;
            float hi   = adet + marg;
            float sm   = m0 + m1 + m2;
            bool maybe = (m0 >= -marg) & (m0 <= hi) &
                         (m1 >= -marg) & (m1 <= hi) &
                         (m2 >= -marg) & (m2 <= hi) &
                         (sm >= -marg) & (sm <= hi) & !found;
            if (maybe) {
                // exact path: true f32 divisions, op-identical to reference
                float l0 = n0 / det;
                float l1 = n1 / det;
                float l2 = n2 / det;
                float l3 = 1.0f - (l0 + l1 + l2);
                bool inside = (l0 >= 0.0f) & (l0 <= 1.0f) &
                              (l1 >= 0.0f) & (l1 <= 1.0f) &
                              (l2 >= 0.0f) & (l2 <= 1.0f) &
                              (l3 >= 0.0f) & (l3 <= 1.0f);
                found = found | inside;
            }
            if (__all(found)) goto done;
        }
    }
done:
    out[(size_t)b * (VWD*VWD*VWD) + (size_t)ix*(VWD*VWD) + iy*VWD + iz]
        = found ? 1.0f : 0.0f;
}

extern "C" void kernel_launch(void* const* d_in, const int* in_sizes, int n_in,
                              void* d_out, int out_size, void* d_ws, size_t ws_size,
                              hipStream_t stream) {
    const float* vertices = (const float*)d_in[0];   // (8, 2048, 3) f32
    const int*   facets   = (const int*)d_in[1];     // (8, 512, 4) int
    float*       out      = (float*)d_out;           // (8, 96, 96, 96) f32

    // d_ws layout: fbb (128 KB) | body (256 KB) | masks (864 KB)
    float* fbb  = (float*)d_ws;
    float* body = (float*)((char*)d_ws + (size_t)NBATCH * NFAC * 8 * 4);
    unsigned long long* msk =
        (unsigned long long*)((char*)d_ws + (size_t)NBATCH * NFAC * 24 * 4);

    precompute_kernel<<<NBATCH, 256, 0, stream>>>(vertices, facets, fbb, body);
    mask_kernel<<<dim3(NSC, NBATCH), 512, 0, stream>>>(fbb, msk);
    dim3 grid(3456, NBATCH);   // 3456 blocks * 4 waves = 13824 cubes per batch
    voxelize_kernel<<<grid, 256, 0, stream>>>(body, msk, out);
}

// Round 4
// 430.426 us; speedup vs baseline: 6.9120x; 1.6635x over previous
//
#include <hip/hip_runtime.h>

// Match numpy f32 semantics: no FMA contraction anywhere in this TU.
#pragma clang fp contract(off)

#define VWD 96
#define NVERT 2048
#define NFAC 512
#define NBATCH 8
#define NSLAB 3456          // 12 x 12 x 24 slabs of 8x8x4 voxels
#define RECF 20             // floats per facet record

// ---------------------------------------------------------------------------
// Kernel 1: per-batch facet precompute, sorted by |det| descending (output is
// an OR over facets -> order-independent; big tets first aids early exit).
// Records are SIGN-FOLDED: if det<0 we negate A and det. IEEE negation
// commutes exactly through mul/add/div, so n'/det' == n/det bit-for-bit and
// the exact path still reproduces the reference.
//   fbb[b][s][8]   : f32 bbox (minx,miny,minz,maxx,maxy,maxz,0,0), +-1e-4
//   body[b][s][20] : det,v3x,v3y,v3z, A00..A22, margA, dhi, mhi, ss0,ss1,ss2,sss
// ---------------------------------------------------------------------------
__global__ __launch_bounds__(256) void precompute_kernel(
    const float* __restrict__ vertices,
    const int*   __restrict__ facets,
    float*       __restrict__ fbb,
    float*       __restrict__ body)
{
    __shared__ unsigned skey[NFAC];
    __shared__ int      sidx[NFAC];
    const int b   = blockIdx.x;
    const int tid = threadIdx.x;
    const float* vb = vertices + (size_t)b * NVERT * 3;

    for (int j = tid; j < NFAC; j += 256) {
        int4 fi = ((const int4*)facets)[b * NFAC + j];
        float x0 = vb[3*fi.x+0], y0 = vb[3*fi.x+1], z0 = vb[3*fi.x+2];
        float x1 = vb[3*fi.y+0], y1 = vb[3*fi.y+1], z1 = vb[3*fi.y+2];
        float x2 = vb[3*fi.z+0], y2 = vb[3*fi.z+1], z2 = vb[3*fi.z+2];
        float x3 = vb[3*fi.w+0], y3 = vb[3*fi.w+1], z3 = vb[3*fi.w+2];
        float a  = x0-x3, bb = x1-x3, c  = x2-x3;
        float d  = y0-y3, e  = y1-y3, f  = y2-y3;
        float g  = z0-z3, h  = z1-z3, ii = z2-z3;
        float det = a*(e*ii - f*h) - bb*(d*ii - f*g) + c*(d*h - e*g);
        skey[j] = ~__float_as_uint(fabsf(det));  // ascending key == descending |det|
        sidx[j] = j;
    }
    __syncthreads();

    for (unsigned k = 2; k <= NFAC; k <<= 1) {
        for (unsigned j = k >> 1; j > 0; j >>= 1) {
            for (int t = tid; t < NFAC; t += 256) {
                int partner = t ^ (int)j;
                if (partner > t) {
                    bool up = ((t & k) == 0);
                    unsigned ka = skey[t], kb2 = skey[partner];
                    if ((ka > kb2) == up) {
                        skey[t] = kb2; skey[partner] = ka;
                        int ia = sidx[t]; sidx[t] = sidx[partner]; sidx[partner] = ia;
                    }
                }
            }
            __syncthreads();
        }
    }

    for (int s = tid; s < NFAC; s += 256) {
        int j = sidx[s];
        int4 fi = ((const int4*)facets)[b * NFAC + j];
        float x0 = vb[3*fi.x+0], y0 = vb[3*fi.x+1], z0 = vb[3*fi.x+2];
        float x1 = vb[3*fi.y+0], y1 = vb[3*fi.y+1], z1 = vb[3*fi.y+2];
        float x2 = vb[3*fi.z+0], y2 = vb[3*fi.z+1], z2 = vb[3*fi.z+2];
        float x3 = vb[3*fi.w+0], y3 = vb[3*fi.w+1], z3 = vb[3*fi.w+2];
        float a  = x0-x3, bb = x1-x3, c  = x2-x3;
        float d  = y0-y3, e  = y1-y3, f  = y2-y3;
        float g  = z0-z3, h  = z1-z3, ii = z2-z3;
        float A00 = e*ii - f*h,  A01 = c*h  - bb*ii, A02 = bb*f - c*e;
        float A10 = f*g  - d*ii, A11 = a*ii - c*g,   A12 = c*d  - a*f;
        float A20 = d*h  - e*g,  A21 = bb*g - a*h,   A22 = a*e  - bb*d;
        float det = a*(e*ii - f*h) - bb*(d*ii - f*g) + c*(d*h - e*g);
        // sign-fold (exact)
        if (det < 0.0f) {
            det = -det;
            A00 = -A00; A01 = -A01; A02 = -A02;
            A10 = -A10; A11 = -A11; A12 = -A12;
            A20 = -A20; A21 = -A21; A22 = -A22;
        }
        float bminx = fminf(fminf(x0,x1),fminf(x2,x3)) - 1e-4f;
        float bminy = fminf(fminf(y0,y1),fminf(y2,y3)) - 1e-4f;
        float bminz = fminf(fminf(z0,z1),fminf(z2,z3)) - 1e-4f;
        float bmaxx = fmaxf(fmaxf(x0,x1),fmaxf(x2,x3)) + 1e-4f;
        float bmaxy = fmaxf(fmaxf(y0,y1),fmaxf(y2,y3)) + 1e-4f;
        float bmaxz = fmaxf(fmaxf(z0,z1),fmaxf(z2,z3)) + 1e-4f;
        float* fb = fbb + ((size_t)b * NFAC + s) * 8;
        fb[0] = bminx; fb[1] = bminy; fb[2] = bminz;
        fb[3] = bmaxx; fb[4] = bmaxy; fb[5] = bmaxz;
        fb[6] = 0.0f;  fb[7] = 0.0f;
        // margins: abs term 1e-3 covers incremental-n error (<=5e-5 rigorous)
        // and all division-rounding slop; rel term covers big-det cases.
        const float DZ = 2.0f / 96.0f;
        float margA = det * 1e-4f + 1e-3f;
        float* bo = body + ((size_t)b * NFAC + s) * RECF;
        bo[0]  = det; bo[1]  = x3;  bo[2]  = y3;  bo[3]  = z3;
        bo[4]  = A00; bo[5]  = A01; bo[6]  = A02;
        bo[7]  = A10; bo[8]  = A11; bo[9]  = A12;
        bo[10] = A20; bo[11] = A21; bo[12] = A22;
        bo[13] = margA;
        bo[14] = det - margA;          // dhi  (definite upper)
        bo[15] = det + margA;          // mhi  (maybe upper)
        float ss0 = A02 * DZ, ss1 = A12 * DZ, ss2 = A22 * DZ;
        bo[16] = ss0; bo[17] = ss1; bo[18] = ss2;
        bo[19] = ss0 + ss1 + ss2;      // sss
    }
}

// ---------------------------------------------------------------------------
// Kernel 2: per-slab (8x8x4 voxels) 512-bit facet mask via ballot.
// ---------------------------------------------------------------------------
__global__ __launch_bounds__(512) void mask_kernel(
    const float* __restrict__ fbb,
    unsigned long long* __restrict__ masks)
{
    const int sc = blockIdx.x;    // 0..3455
    const int b  = blockIdx.y;
    const int f  = threadIdx.x;
    const float* fb = fbb + ((size_t)b * NFAC + f) * 8;
    float bminx = fb[0], bminy = fb[1], bminz = fb[2];
    float bmaxx = fb[3], bmaxy = fb[4], bmaxz = fb[5];
    const int sz = sc % 24, sy = (sc / 24) % 12, sx = sc / 288;
    const float scminx = (float)(16*sx + 1 - VWD) / 96.0f;
    const float scmaxx = (float)(16*sx + 15 - VWD) / 96.0f;
    const float scminy = (float)(16*sy + 1 - VWD) / 96.0f;
    const float scmaxy = (float)(16*sy + 15 - VWD) / 96.0f;
    const float scminz = (float)(8*sz + 1 - VWD) / 96.0f;
    const float scmaxz = (float)(8*sz + 7 - VWD) / 96.0f;
    bool ov = (bminx <= scmaxx) & (bmaxx >= scminx) &
              (bminy <= scmaxy) & (bmaxy >= scminy) &
              (bminz <= scmaxz) & (bmaxz >= scminz);
    unsigned long long bal = __ballot((int)ov);
    if ((threadIdx.x & 63) == 0)
        masks[((size_t)b * NSLAB + sc) * 8 + (threadIdx.x >> 6)] = bal;
}

// ---------------------------------------------------------------------------
// Kernel 3: one wave per 8x8x4 slab (4 z-voxels per lane). Candidates from
// the slab bitmask; per candidate, base n computed exactly once, z-neighbors
// incrementally (margin-protected); definite-inside shortcut avoids divisions;
// exact ref path only for the ~1e-3 uncertainty shell.
// ---------------------------------------------------------------------------
__global__ __launch_bounds__(256) void voxelize_kernel(
    const float*              __restrict__ body,
    const unsigned long long* __restrict__ masks,
    float*                    __restrict__ out)
{
    const int b    = blockIdx.y;
    const int wave = threadIdx.x >> 6;
    const int lane = threadIdx.x & 63;
    const int slab = blockIdx.x * 4 + wave;          // 0 .. 3455
    const int sz = slab % 24;
    const int sy = (slab / 24) % 12;
    const int sx = slab / 288;
    const int ix  = sx*8 + (lane >> 3);
    const int iy  = sy*8 + (lane & 7);
    const int iz0 = sz*4;

    const float px  = (float)(2*ix  + 1 - VWD) / 96.0f;
    const float py  = (float)(2*iy  + 1 - VWD) / 96.0f;
    const float pz0 = (float)(2*iz0 + 1 - VWD) / 96.0f;

    const unsigned long long* mp = masks + ((size_t)b * NSLAB + slab) * 8;
    const float* bb = body + (size_t)b * NFAC * RECF;

    unsigned fnd = 0u;   // bit k = voxel (ix,iy,iz0+k) found
    for (int w = 0; w < 8; ++w) {
        unsigned long long m = mp[w];   // wave-uniform -> SGPR
        while (m) {
            int bit = __builtin_ctzll(m);
            m &= m - 1;
            int f = __builtin_amdgcn_readfirstlane(w * 64 + bit);
            const float* bo = bb + f * RECF;
            float det = bo[0], v3x = bo[1], v3y = bo[2], v3z = bo[3];
            float A00 = bo[4],  A01 = bo[5],  A02 = bo[6];
            float A10 = bo[7],  A11 = bo[8],  A12 = bo[9];
            float A20 = bo[10], A21 = bo[11], A22 = bo[12];
            float margA = bo[13], dhi = bo[14], mhi = bo[15];
            float ss0 = bo[16], ss1 = bo[17], ss2 = bo[18], sss = bo[19];
            float dx = px - v3x, dy = py - v3y, dz0 = pz0 - v3z;
            // ref-exact at k=0 (left-assoc)
            float n0 = A00*dx + A01*dy + A02*dz0;
            float n1 = A10*dx + A11*dy + A12*dz0;
            float n2 = A20*dx + A21*dy + A22*dz0;
            float sm = n0 + n1 + n2;
            float nmargA = -margA;
#pragma unroll
            for (int k = 0; k < 4; ++k) {
                float mn = fminf(fminf(n0, n1), fminf(n2, sm));
                float mx = fmaxf(fmaxf(n0, n1), fmaxf(n2, sm));
                // definite: rigorously implies ref-inside (no divisions)
                bool def = (mn >= margA) & (mx <= dhi);
                // maybe: rigorously implied by ref-inside
                bool may = (mn >= nmargA) & (mx <= mhi);
                bool needex = may & !def & !((fnd >> k) & 1u);
                if (__any(needex)) {
                    // exact path: op-identical to reference (sign-folding
                    // commutes exactly through IEEE mul/add/div)
                    int izk = iz0 + k;
                    float pzk = (float)(2*izk + 1 - VWD) / 96.0f;
                    float dzk = pzk - v3z;
                    float e0 = A00*dx + A01*dy + A02*dzk;
                    float e1 = A10*dx + A11*dy + A12*dzk;
                    float e2 = A20*dx + A21*dy + A22*dzk;
                    float l0 = e0 / det;
                    float l1 = e1 / det;
                    float l2 = e2 / det;
                    float l3 = 1.0f - (l0 + l1 + l2);
                    bool inside = (l0 >= 0.0f) & (l0 <= 1.0f) &
                                  (l1 >= 0.0f) & (l1 <= 1.0f) &
                                  (l2 >= 0.0f) & (l2 <= 1.0f) &
                                  (l3 >= 0.0f) & (l3 <= 1.0f);
                    if (needex & inside) fnd |= (1u << k);
                }
                if (def) fnd |= (1u << k);
                if (k < 3) { n0 += ss0; n1 += ss1; n2 += ss2; sm += sss; }
            }
            if (__all(fnd == 15u)) goto done;
        }
    }
done:
    float4 v;
    v.x = (fnd & 1u) ? 1.0f : 0.0f;
    v.y = (fnd & 2u) ? 1.0f : 0.0f;
    v.z = (fnd & 4u) ? 1.0f : 0.0f;
    v.w = (fnd & 8u) ? 1.0f : 0.0f;
    *(float4*)&out[(size_t)b*(VWD*VWD*VWD) + (size_t)ix*(VWD*VWD) + iy*VWD + iz0] = v;
}

extern "C" void kernel_launch(void* const* d_in, const int* in_sizes, int n_in,
                              void* d_out, int out_size, void* d_ws, size_t ws_size,
                              hipStream_t stream) {
    const float* vertices = (const float*)d_in[0];   // (8, 2048, 3) f32
    const int*   facets   = (const int*)d_in[1];     // (8, 512, 4) int
    float*       out      = (float*)d_out;           // (8, 96, 96, 96) f32

    // d_ws layout: fbb (128 KB) | body (320 KB) | masks (1.77 MB)
    float* fbb  = (float*)d_ws;
    float* body = (float*)((char*)d_ws + (size_t)NBATCH * NFAC * 8 * 4);
    unsigned long long* msk =
        (unsigned long long*)((char*)d_ws + (size_t)NBATCH * NFAC * (8 + RECF) * 4);

    precompute_kernel<<<NBATCH, 256, 0, stream>>>(vertices, facets, fbb, body);
    mask_kernel<<<dim3(NSLAB, NBATCH), 512, 0, stream>>>(fbb, msk);
    dim3 grid(NSLAB / 4, NBATCH);   // 864 blocks * 4 waves = 3456 slabs/batch
    voxelize_kernel<<<grid, 256, 0, stream>>>(body, msk, out);
}

// Round 5
// 197.607 us; speedup vs baseline: 15.0556x; 2.1782x over previous
//
#include <hip/hip_runtime.h>

// Match numpy f32 semantics: no FMA contraction anywhere in this TU.
#pragma clang fp contract(off)

#define VWD 96
#define NVERT 2048
#define NFAC 512
#define NBATCH 8
#define NSLAB 3456          // 12 x 12 x 24 slabs of 8x8x4 voxels
#define RECF 20             // floats per facet body record
#define CULF 24             // floats per facet cull record (bbox + 4 planes)

// ---------------------------------------------------------------------------
// Kernel 1: per-batch facet precompute, sorted by |det| descending (output is
// an OR over facets -> order-independent; big tets first aids early exit).
// Body records are SIGN-FOLDED: if det<0 we negate A and det. IEEE negation
// commutes exactly through mul/add/div, so n'/det' == n/det bit-for-bit.
//   cul[b][s][24]  : bbox(minx,miny,minz,maxx,maxy,maxz) + 4x(nx,ny,nz,d')
//   body[b][s][20] : det,v3x,v3y,v3z, A00..A22, margA, dhi, mhi, ss0,ss1,ss2,sss
// ---------------------------------------------------------------------------
__global__ __launch_bounds__(256) void precompute_kernel(
    const float* __restrict__ vertices,
    const int*   __restrict__ facets,
    float*       __restrict__ cul,
    float*       __restrict__ body)
{
    __shared__ unsigned skey[NFAC];
    __shared__ int      sidx[NFAC];
    const int b   = blockIdx.x;
    const int tid = threadIdx.x;
    const float* vb = vertices + (size_t)b * NVERT * 3;

    for (int j = tid; j < NFAC; j += 256) {
        int4 fi = ((const int4*)facets)[b * NFAC + j];
        float x0 = vb[3*fi.x+0], y0 = vb[3*fi.x+1], z0 = vb[3*fi.x+2];
        float x1 = vb[3*fi.y+0], y1 = vb[3*fi.y+1], z1 = vb[3*fi.y+2];
        float x2 = vb[3*fi.z+0], y2 = vb[3*fi.z+1], z2 = vb[3*fi.z+2];
        float x3 = vb[3*fi.w+0], y3 = vb[3*fi.w+1], z3 = vb[3*fi.w+2];
        float a  = x0-x3, bb = x1-x3, c  = x2-x3;
        float d  = y0-y3, e  = y1-y3, f  = y2-y3;
        float g  = z0-z3, h  = z1-z3, ii = z2-z3;
        float det = a*(e*ii - f*h) - bb*(d*ii - f*g) + c*(d*h - e*g);
        skey[j] = ~__float_as_uint(fabsf(det));  // ascending key == descending |det|
        sidx[j] = j;
    }
    __syncthreads();

    for (unsigned k = 2; k <= NFAC; k <<= 1) {
        for (unsigned j = k >> 1; j > 0; j >>= 1) {
            for (int t = tid; t < NFAC; t += 256) {
                int partner = t ^ (int)j;
                if (partner > t) {
                    bool up = ((t & k) == 0);
                    unsigned ka = skey[t], kb2 = skey[partner];
                    if ((ka > kb2) == up) {
                        skey[t] = kb2; skey[partner] = ka;
                        int ia = sidx[t]; sidx[t] = sidx[partner]; sidx[partner] = ia;
                    }
                }
            }
            __syncthreads();
        }
    }

    for (int s = tid; s < NFAC; s += 256) {
        int j = sidx[s];
        int4 fi = ((const int4*)facets)[b * NFAC + j];
        float vx[4], vy[4], vz[4];
        vx[0]=vb[3*fi.x+0]; vy[0]=vb[3*fi.x+1]; vz[0]=vb[3*fi.x+2];
        vx[1]=vb[3*fi.y+0]; vy[1]=vb[3*fi.y+1]; vz[1]=vb[3*fi.y+2];
        vx[2]=vb[3*fi.z+0]; vy[2]=vb[3*fi.z+1]; vz[2]=vb[3*fi.z+2];
        vx[3]=vb[3*fi.w+0]; vy[3]=vb[3*fi.w+1]; vz[3]=vb[3*fi.w+2];
        float x0=vx[0], y0=vy[0], z0=vz[0];
        float x1=vx[1], y1=vy[1], z1=vz[1];
        float x2=vx[2], y2=vy[2], z2=vz[2];
        float x3=vx[3], y3=vy[3], z3=vz[3];
        float a  = x0-x3, bb = x1-x3, c  = x2-x3;
        float d  = y0-y3, e  = y1-y3, f  = y2-y3;
        float g  = z0-z3, h  = z1-z3, ii = z2-z3;
        float A00 = e*ii - f*h,  A01 = c*h  - bb*ii, A02 = bb*f - c*e;
        float A10 = f*g  - d*ii, A11 = a*ii - c*g,   A12 = c*d  - a*f;
        float A20 = d*h  - e*g,  A21 = bb*g - a*h,   A22 = a*e  - bb*d;
        float det = a*(e*ii - f*h) - bb*(d*ii - f*g) + c*(d*h - e*g);
        if (det < 0.0f) {   // sign-fold (exact)
            det = -det;
            A00 = -A00; A01 = -A01; A02 = -A02;
            A10 = -A10; A11 = -A11; A12 = -A12;
            A20 = -A20; A21 = -A21; A22 = -A22;
        }
        float* cu = cul + ((size_t)b * NFAC + s) * CULF;
        cu[0] = fminf(fminf(x0,x1),fminf(x2,x3)) - 1e-4f;
        cu[1] = fminf(fminf(y0,y1),fminf(y2,y3)) - 1e-4f;
        cu[2] = fminf(fminf(z0,z1),fminf(z2,z3)) - 1e-4f;
        cu[3] = fmaxf(fmaxf(x0,x1),fmaxf(x2,x3)) + 1e-4f;
        cu[4] = fmaxf(fmaxf(y0,y1),fmaxf(y2,y3)) + 1e-4f;
        cu[5] = fmaxf(fmaxf(z0,z1),fmaxf(z2,z3)) + 1e-4f;
        // 4 outward face planes, margin-inflated (conservative: keep-region
        // strictly contains every point whose ref-inside could be true)
        const int fa[4] = {1,0,0,0}, fbv[4] = {2,2,1,1}, fc[4] = {3,3,3,2};
        for (int p = 0; p < 4; ++p) {
            int ia = fa[p], ib = fbv[p], ic = fc[p], io = p;
            float e1x = vx[ib]-vx[ia], e1y = vy[ib]-vy[ia], e1z = vz[ib]-vz[ia];
            float e2x = vx[ic]-vx[ia], e2y = vy[ic]-vy[ia], e2z = vz[ic]-vz[ia];
            float nx = e1y*e2z - e1z*e2y;
            float ny = e1z*e2x - e1x*e2z;
            float nz = e1x*e2y - e1y*e2x;
            float sdot = nx*(vx[io]-vx[ia]) + ny*(vy[io]-vy[ia]) + nz*(vz[io]-vz[ia]);
            if (sdot > 0.0f) { nx=-nx; ny=-ny; nz=-nz; sdot=-sdot; }
            float dpl = nx*vx[ia] + ny*vy[ia] + nz*vz[ia];
            float M = 1e-4f*(-sdot) + 1e-4f*(fabsf(nx)+fabsf(ny)+fabsf(nz)) + 1e-4f;
            cu[6+p*4+0] = nx; cu[6+p*4+1] = ny; cu[6+p*4+2] = nz;
            cu[6+p*4+3] = dpl + M;
        }
        cu[22] = 0.0f; cu[23] = 0.0f;
        const float DZ = 2.0f / 96.0f;
        float margA = det * 1e-4f + 1e-3f;
        float* bo = body + ((size_t)b * NFAC + s) * RECF;
        bo[0]  = det; bo[1]  = x3;  bo[2]  = y3;  bo[3]  = z3;
        bo[4]  = A00; bo[5]  = A01; bo[6]  = A02;
        bo[7]  = A10; bo[8]  = A11; bo[9]  = A12;
        bo[10] = A20; bo[11] = A21; bo[12] = A22;
        bo[13] = margA;
        bo[14] = det - margA;          // dhi  (definite upper)
        bo[15] = det + margA;          // mhi  (maybe upper)
        float ss0 = A02 * DZ, ss1 = A12 * DZ, ss2 = A22 * DZ;
        bo[16] = ss0; bo[17] = ss1; bo[18] = ss2;
        bo[19] = ss0 + ss1 + ss2;      // sss
    }
}

// ---------------------------------------------------------------------------
// Kernel 2: per-slab (8x8x4 voxels) 512-bit facet mask via ballot.
// bbox overlap AND all-4-face-plane overlap (conservative SAT subset).
// ---------------------------------------------------------------------------
__global__ __launch_bounds__(512) void mask_kernel(
    const float* __restrict__ cul,
    unsigned long long* __restrict__ masks)
{
    const int sc = blockIdx.x;    // 0..3455
    const int b  = blockIdx.y;
    const int f  = threadIdx.x;
    const float* cu = cul + ((size_t)b * NFAC + f) * CULF;
    const int sz = sc % 24, sy = (sc / 24) % 12, sx = sc / 288;
    const float scminx = (float)(16*sx + 1 - VWD) / 96.0f;
    const float scmaxx = (float)(16*sx + 15 - VWD) / 96.0f;
    const float scminy = (float)(16*sy + 1 - VWD) / 96.0f;
    const float scmaxy = (float)(16*sy + 15 - VWD) / 96.0f;
    const float scminz = (float)(8*sz + 1 - VWD) / 96.0f;
    const float scmaxz = (float)(8*sz + 7 - VWD) / 96.0f;
    bool ov = (cu[0] <= scmaxx) & (cu[3] >= scminx) &
              (cu[1] <= scmaxy) & (cu[4] >= scminy) &
              (cu[2] <= scmaxz) & (cu[5] >= scminz);
    const float cx = 0.5f*(scminx+scmaxx), hx = 0.5f*(scmaxx-scminx);
    const float cy = 0.5f*(scminy+scmaxy), hy = 0.5f*(scmaxy-scminy);
    const float cz = 0.5f*(scminz+scmaxz), hz = 0.5f*(scmaxz-scminz);
#pragma unroll
    for (int p = 0; p < 4; ++p) {
        float nx = cu[6+p*4+0], ny = cu[6+p*4+1], nz = cu[6+p*4+2];
        float dp = cu[6+p*4+3];
        float lo = nx*cx + ny*cy + nz*cz
                 - (fabsf(nx)*hx + fabsf(ny)*hy + fabsf(nz)*hz);
        ov = ov & (lo <= dp);
    }
    unsigned long long bal = __ballot((int)ov);
    if ((threadIdx.x & 63) == 0)
        masks[((size_t)b * NSLAB + sc) * 8 + (threadIdx.x >> 6)] = bal;
}

// ---------------------------------------------------------------------------
// Kernel 3: one wave per 8x8x4 slab (4 z-voxels per lane). Candidates from
// the slab bitmask; base n computed once per candidate, z-neighbors
// incrementally (margin-protected); test reduced to min3+sum (sign-folded
// det>0: n_i in [0,det] & sm in [0,det]  <=>  min3(n)>=0 & sm<=det, since
// n_i <= sm <= det follows from the other two n >= 0); definite-inside
// shortcut avoids divisions; exact ref path only for the ~1e-3 shell.
// ---------------------------------------------------------------------------
__global__ __launch_bounds__(256) void voxelize_kernel(
    const float*              __restrict__ body,
    const unsigned long long* __restrict__ masks,
    float*                    __restrict__ out)
{
    const int b    = blockIdx.y;
    const int wave = threadIdx.x >> 6;
    const int lane = threadIdx.x & 63;
    const int slab = blockIdx.x * 4 + wave;          // 0 .. 3455
    const int sz = slab % 24;
    const int sy = (slab / 24) % 12;
    const int sx = slab / 288;
    const int ix  = sx*8 + (lane >> 3);
    const int iy  = sy*8 + (lane & 7);
    const int iz0 = sz*4;

    const float px  = (float)(2*ix  + 1 - VWD) / 96.0f;
    const float py  = (float)(2*iy  + 1 - VWD) / 96.0f;
    const float pz0 = (float)(2*iz0 + 1 - VWD) / 96.0f;

    const unsigned long long* mp = masks + ((size_t)b * NSLAB + slab) * 8;
    const float* bb = body + (size_t)b * NFAC * RECF;

    unsigned fnd = 0u;   // bit k = voxel (ix,iy,iz0+k) found
    for (int w = 0; w < 8; ++w) {
        unsigned long long m = mp[w];   // wave-uniform -> SGPR
        while (m) {
            int bit = __builtin_ctzll(m);
            m &= m - 1;
            int f = __builtin_amdgcn_readfirstlane(w * 64 + bit);
            const float* bo = bb + f * RECF;
            float det = bo[0], v3x = bo[1], v3y = bo[2], v3z = bo[3];
            float A00 = bo[4],  A01 = bo[5],  A02 = bo[6];
            float A10 = bo[7],  A11 = bo[8],  A12 = bo[9];
            float A20 = bo[10], A21 = bo[11], A22 = bo[12];
            float margA = bo[13], dhi = bo[14], mhi = bo[15];
            float ss0 = bo[16], ss1 = bo[17], ss2 = bo[18], sss = bo[19];
            float dx = px - v3x, dy = py - v3y, dz0 = pz0 - v3z;
            // ref-exact at k=0 (left-assoc)
            float n0 = A00*dx + A01*dy + A02*dz0;
            float n1 = A10*dx + A11*dy + A12*dz0;
            float n2 = A20*dx + A21*dy + A22*dz0;
            float sm = n0 + n1 + n2;
            float nmargA = -margA;
#pragma unroll
            for (int k = 0; k < 4; ++k) {
                float mn = fminf(fminf(n0, n1), n2);   // v_min3_f32
                // definite: rigorously implies ref-inside (no divisions):
                //   each n_i >= margA > 0 and sm <= det-margA  =>  each
                //   e_i/det rounds into (0,1), sum of l rounds below 1.
                bool def = (mn >= margA) & (sm <= dhi);
                // maybe: rigorously implied by ref-inside (n error <=1e-5,
                // quotient slop <= det*1e-7; margA = det*1e-4+1e-3 dwarfs).
                bool may = (mn >= nmargA) & (sm <= mhi);
                bool needex = may & !def & !((fnd >> k) & 1u);
                if (__any(needex)) {
                    // exact path: op-identical to reference (sign-folding
                    // commutes exactly through IEEE mul/add/div)
                    int izk = iz0 + k;
                    float pzk = (float)(2*izk + 1 - VWD) / 96.0f;
                    float dzk = pzk - v3z;
                    float e0 = A00*dx + A01*dy + A02*dzk;
                    float e1 = A10*dx + A11*dy + A12*dzk;
                    float e2 = A20*dx + A21*dy + A22*dzk;
                    float l0 = e0 / det;
                    float l1 = e1 / det;
                    float l2 = e2 / det;
                    float l3 = 1.0f - (l0 + l1 + l2);
                    bool inside = (l0 >= 0.0f) & (l0 <= 1.0f) &
                                  (l1 >= 0.0f) & (l1 <= 1.0f) &
                                  (l2 >= 0.0f) & (l2 <= 1.0f) &
                                  (l3 >= 0.0f) & (l3 <= 1.0f);
                    if (needex & inside) fnd |= (1u << k);
                }
                if (def) fnd |= (1u << k);
                if (k < 3) { n0 += ss0; n1 += ss1; n2 += ss2; sm += sss; }
            }
            if (__all(fnd == 15u)) goto done;
        }
    }
done:
    float4 v;
    v.x = (fnd & 1u) ? 1.0f : 0.0f;
    v.y = (fnd & 2u) ? 1.0f : 0.0f;
    v.z = (fnd & 4u) ? 1.0f : 0.0f;
    v.w = (fnd & 8u) ? 1.0f : 0.0f;
    *(float4*)&out[(size_t)b*(VWD*VWD*VWD) + (size_t)ix*(VWD*VWD) + iy*VWD + iz0] = v;
}

extern "C" void kernel_launch(void* const* d_in, const int* in_sizes, int n_in,
                              void* d_out, int out_size, void* d_ws, size_t ws_size,
                              hipStream_t stream) {
    const float* vertices = (const float*)d_in[0];   // (8, 2048, 3) f32
    const int*   facets   = (const int*)d_in[1];     // (8, 512, 4) int
    float*       out      = (float*)d_out;           // (8, 96, 96, 96) f32

    // d_ws layout: cul (384 KB) | body (320 KB) | masks (1.77 MB)
    float* cul  = (float*)d_ws;
    float* body = (float*)((char*)d_ws + (size_t)NBATCH * NFAC * CULF * 4);
    unsigned long long* msk =
        (unsigned long long*)((char*)d_ws + (size_t)NBATCH * NFAC * (CULF + RECF) * 4);

    precompute_kernel<<<NBATCH, 256, 0, stream>>>(vertices, facets, cul, body);
    mask_kernel<<<dim3(NSLAB, NBATCH), 512, 0, stream>>>(cul, msk);
    dim3 grid(NSLAB / 4, NBATCH);   // 864 blocks * 4 waves = 3456 slabs/batch
    voxelize_kernel<<<grid, 256, 0, stream>>>(body, msk, out);
}

// Round 6
// 146.339 us; speedup vs baseline: 20.3301x; 1.3503x over previous
//
#include <hip/hip_runtime.h>

// Match numpy f32 semantics: no FMA contraction anywhere in this TU.
#pragma clang fp contract(off)

#define VWD 96
#define NVERT 2048
#define NFAC 512
#define NBATCH 8
#define NSLAB 3456          // 12 x 12 x 24 slabs of 8x8x4 voxels
#define RECF 20             // floats per facet body record
#define CULF 24             // floats per facet cull record (bbox + 4 planes)

// ---------------------------------------------------------------------------
// Kernel 1: per-batch facet precompute, sorted by |det| descending (output is
// an OR over facets -> order-independent; big tets first aids early exit).
// Body records are SIGN-FOLDED: if det<0 we negate A and det. IEEE negation
// commutes exactly through mul/add/div, so n'/det' == n/det bit-for-bit.
//   cul[b][s][24]  : bbox(minx,miny,minz,maxx,maxy,maxz) + 4x(nx,ny,nz,rhs)
//                    rhs = d + margin + |n|.h_slab  (slab half-extents folded)
//   body[b][s][20] : det,v3x,v3y,v3z, A00..A22, margA, dhi, mhi, ss0,ss1,ss2,sss
// ---------------------------------------------------------------------------
__global__ __launch_bounds__(512) void precompute_kernel(
    const float* __restrict__ vertices,
    const int*   __restrict__ facets,
    float*       __restrict__ cul,
    float*       __restrict__ body)
{
    __shared__ unsigned skey[NFAC];
    __shared__ int      sidx[NFAC];
    const int b   = blockIdx.x;
    const int tid = threadIdx.x;
    const float* vb = vertices + (size_t)b * NVERT * 3;

    for (int j = tid; j < NFAC; j += 512) {
        int4 fi = ((const int4*)facets)[b * NFAC + j];
        float x0 = vb[3*fi.x+0], y0 = vb[3*fi.x+1], z0 = vb[3*fi.x+2];
        float x1 = vb[3*fi.y+0], y1 = vb[3*fi.y+1], z1 = vb[3*fi.y+2];
        float x2 = vb[3*fi.z+0], y2 = vb[3*fi.z+1], z2 = vb[3*fi.z+2];
        float x3 = vb[3*fi.w+0], y3 = vb[3*fi.w+1], z3 = vb[3*fi.w+2];
        float a  = x0-x3, bb = x1-x3, c  = x2-x3;
        float d  = y0-y3, e  = y1-y3, f  = y2-y3;
        float g  = z0-z3, h  = z1-z3, ii = z2-z3;
        float det = a*(e*ii - f*h) - bb*(d*ii - f*g) + c*(d*h - e*g);
        skey[j] = ~__float_as_uint(fabsf(det));  // ascending key == descending |det|
        sidx[j] = j;
    }
    __syncthreads();

    for (unsigned k = 2; k <= NFAC; k <<= 1) {
        for (unsigned j = k >> 1; j > 0; j >>= 1) {
            for (int t = tid; t < NFAC; t += 512) {
                int partner = t ^ (int)j;
                if (partner > t) {
                    bool up = ((t & k) == 0);
                    unsigned ka = skey[t], kb2 = skey[partner];
                    if ((ka > kb2) == up) {
                        skey[t] = kb2; skey[partner] = ka;
                        int ia = sidx[t]; sidx[t] = sidx[partner]; sidx[partner] = ia;
                    }
                }
            }
            __syncthreads();
        }
    }

    for (int s = tid; s < NFAC; s += 512) {
        int j = sidx[s];
        int4 fi = ((const int4*)facets)[b * NFAC + j];
        float vx[4], vy[4], vz[4];
        vx[0]=vb[3*fi.x+0]; vy[0]=vb[3*fi.x+1]; vz[0]=vb[3*fi.x+2];
        vx[1]=vb[3*fi.y+0]; vy[1]=vb[3*fi.y+1]; vz[1]=vb[3*fi.y+2];
        vx[2]=vb[3*fi.z+0]; vy[2]=vb[3*fi.z+1]; vz[2]=vb[3*fi.z+2];
        vx[3]=vb[3*fi.w+0]; vy[3]=vb[3*fi.w+1]; vz[3]=vb[3*fi.w+2];
        float x0=vx[0], y0=vy[0], z0=vz[0];
        float x1=vx[1], y1=vy[1], z1=vz[1];
        float x2=vx[2], y2=vy[2], z2=vz[2];
        float x3=vx[3], y3=vy[3], z3=vz[3];
        float a  = x0-x3, bb = x1-x3, c  = x2-x3;
        float d  = y0-y3, e  = y1-y3, f  = y2-y3;
        float g  = z0-z3, h  = z1-z3, ii = z2-z3;
        float A00 = e*ii - f*h,  A01 = c*h  - bb*ii, A02 = bb*f - c*e;
        float A10 = f*g  - d*ii, A11 = a*ii - c*g,   A12 = c*d  - a*f;
        float A20 = d*h  - e*g,  A21 = bb*g - a*h,   A22 = a*e  - bb*d;
        float det = a*(e*ii - f*h) - bb*(d*ii - f*g) + c*(d*h - e*g);
        if (det < 0.0f) {   // sign-fold (exact)
            det = -det;
            A00 = -A00; A01 = -A01; A02 = -A02;
            A10 = -A10; A11 = -A11; A12 = -A12;
            A20 = -A20; A21 = -A21; A22 = -A22;
        }
        float* cu = cul + ((size_t)b * NFAC + s) * CULF;
        cu[0] = fminf(fminf(x0,x1),fminf(x2,x3)) - 1e-4f;
        cu[1] = fminf(fminf(y0,y1),fminf(y2,y3)) - 1e-4f;
        cu[2] = fminf(fminf(z0,z1),fminf(z2,z3)) - 1e-4f;
        cu[3] = fmaxf(fmaxf(x0,x1),fmaxf(x2,x3)) + 1e-4f;
        cu[4] = fmaxf(fmaxf(y0,y1),fmaxf(y2,y3)) + 1e-4f;
        cu[5] = fmaxf(fmaxf(z0,z1),fmaxf(z2,z3)) + 1e-4f;
        // 4 outward face planes, margin-inflated, slab half-extents folded:
        // mask test becomes  dot(n, slab_center) <= rhs  (conservative).
        const float HX = 7.0f/96.0f, HZ = 3.0f/96.0f;
        const int fa[4] = {1,0,0,0}, fbv[4] = {2,2,1,1}, fc[4] = {3,3,3,2};
        for (int p = 0; p < 4; ++p) {
            int ia = fa[p], ib = fbv[p], ic = fc[p], io = p;
            float e1x = vx[ib]-vx[ia], e1y = vy[ib]-vy[ia], e1z = vz[ib]-vz[ia];
            float e2x = vx[ic]-vx[ia], e2y = vy[ic]-vy[ia], e2z = vz[ic]-vz[ia];
            float nx = e1y*e2z - e1z*e2y;
            float ny = e1z*e2x - e1x*e2z;
            float nz = e1x*e2y - e1y*e2x;
            float sdot = nx*(vx[io]-vx[ia]) + ny*(vy[io]-vy[ia]) + nz*(vz[io]-vz[ia]);
            if (sdot > 0.0f) { nx=-nx; ny=-ny; nz=-nz; sdot=-sdot; }
            float dpl = nx*vx[ia] + ny*vy[ia] + nz*vz[ia];
            float n1s = fabsf(nx)+fabsf(ny)+fabsf(nz);
            float M = 1e-4f*(-sdot) + 1e-4f*n1s + 1e-4f;   // covers vertex slop,
                                                           // incremental-dot error
            float rhs = dpl + M + (fabsf(nx)*HX + fabsf(ny)*HX + fabsf(nz)*HZ);
            cu[6+p*4+0] = nx; cu[6+p*4+1] = ny; cu[6+p*4+2] = nz;
            cu[6+p*4+3] = rhs;
        }
        cu[22] = 0.0f; cu[23] = 0.0f;
        const float DZ = 2.0f / 96.0f;
        float margA = det * 1e-4f + 1e-3f;
        float* bo = body + ((size_t)b * NFAC + s) * RECF;
        bo[0]  = det; bo[1]  = x3;  bo[2]  = y3;  bo[3]  = z3;
        bo[4]  = A00; bo[5]  = A01; bo[6]  = A02;
        bo[7]  = A10; bo[8]  = A11; bo[9]  = A12;
        bo[10] = A20; bo[11] = A21; bo[12] = A22;
        bo[13] = margA;
        bo[14] = det - margA;          // dhi  (definite upper)
        bo[15] = det + margA;          // mhi  (maybe upper)
        float ss0 = A02 * DZ, ss1 = A12 * DZ, ss2 = A22 * DZ;
        bo[16] = ss0; bo[17] = ss1; bo[18] = ss2;
        bo[19] = ss0 + ss1 + ss2;      // sss
    }
}

// ---------------------------------------------------------------------------
// Kernel 2: per-slab 512-bit facet mask. One block per (batch, x-y column);
// facet-per-lane, cull record loaded ONCE into VGPRs, then the column's 24
// z-slabs tested with incremental plane dots (error ~3e-6 << 1e-4 margin).
// ---------------------------------------------------------------------------
__global__ __launch_bounds__(512) void mask_kernel(
    const float* __restrict__ cul,
    unsigned long long* __restrict__ masks)
{
    const int col = blockIdx.x;           // 0..143 = sx*12+sy
    const int b   = blockIdx.y;
    const int f   = threadIdx.x;          // facet (sorted order)
    const int w   = threadIdx.x >> 6;
    const float* cu = cul + ((size_t)b * NFAC + f) * CULF;
    float bminx=cu[0], bminy=cu[1], bminz=cu[2];
    float bmaxx=cu[3], bmaxy=cu[4], bmaxz=cu[5];
    float n0x=cu[6],  n0y=cu[7],  n0z=cu[8],  r0=cu[9];
    float n1x=cu[10], n1y=cu[11], n1z=cu[12], r1=cu[13];
    float n2x=cu[14], n2y=cu[15], n2z=cu[16], r2=cu[17];
    float n3x=cu[18], n3y=cu[19], n3z=cu[20], r3=cu[21];

    const int sx = col / 12, sy = col % 12;
    const float cx = (float)(16*sx + 8 - VWD) / 96.0f;
    const float cy = (float)(16*sy + 8 - VWD) / 96.0f;
    const float colminx = (float)(16*sx + 1  - VWD) / 96.0f;
    const float colmaxx = (float)(16*sx + 15 - VWD) / 96.0f;
    const float colminy = (float)(16*sy + 1  - VWD) / 96.0f;
    const float colmaxy = (float)(16*sy + 15 - VWD) / 96.0f;
    const bool ovxy = (bminx <= colmaxx) & (bmaxx >= colminx) &
                      (bminy <= colmaxy) & (bmaxy >= colminy);

    const float cz0   = (float)(4 - VWD) / 96.0f;   // z-center of slab sz=0
    const float stepc = 8.0f / 96.0f;
    float d0 = n0x*cx + n0y*cy + n0z*cz0 - r0;  float s0 = n0z*stepc;
    float d1 = n1x*cx + n1y*cy + n1z*cz0 - r1;  float s1 = n1z*stepc;
    float d2 = n2x*cx + n2y*cy + n2z*cz0 - r2;  float s2 = n2z*stepc;
    float d3 = n3x*cx + n3y*cy + n3z*cz0 - r3;  float s3 = n3z*stepc;
    float zlo = (float)(1 - VWD) / 96.0f;
    float zhi = (float)(7 - VWD) / 96.0f;

    unsigned long long* mp = masks + ((size_t)b * NSLAB + (size_t)col * 24) * 8 + w;
#pragma unroll 4
    for (int sz = 0; sz < 24; ++sz) {
        bool ov = ovxy & (bminz <= zhi) & (bmaxz >= zlo) &
                  (d0 <= 0.0f) & (d1 <= 0.0f) & (d2 <= 0.0f) & (d3 <= 0.0f);
        unsigned long long bal = __ballot((int)ov);
        if ((threadIdx.x & 63) == 0) mp[(size_t)sz * 8] = bal;
        d0 += s0; d1 += s1; d2 += s2; d3 += s3;
        zlo += stepc; zhi += stepc;
    }
}

// ---------------------------------------------------------------------------
// Kernel 3: one wave per 8x8x4 slab (4 z-voxels per lane). Candidates from
// the slab bitmask; base n computed once per candidate, z-neighbors
// incrementally (margin-protected); test reduced to min3+sum; definite-inside
// shortcut avoids divisions; exact ref path only for the ~1e-3 shell.
// ---------------------------------------------------------------------------
__global__ __launch_bounds__(256) void voxelize_kernel(
    const float*              __restrict__ body,
    const unsigned long long* __restrict__ masks,
    float*                    __restrict__ out)
{
    const int b    = blockIdx.y;
    const int wave = threadIdx.x >> 6;
    const int lane = threadIdx.x & 63;
    const int slab = blockIdx.x * 4 + wave;          // 0 .. 3455
    const int sz = slab % 24;
    const int sy = (slab / 24) % 12;
    const int sx = slab / 288;
    const int ix  = sx*8 + (lane >> 3);
    const int iy  = sy*8 + (lane & 7);
    const int iz0 = sz*4;

    const float px  = (float)(2*ix  + 1 - VWD) / 96.0f;
    const float py  = (float)(2*iy  + 1 - VWD) / 96.0f;
    const float pz0 = (float)(2*iz0 + 1 - VWD) / 96.0f;

    const unsigned long long* mp = masks + ((size_t)b * NSLAB + slab) * 8;
    const float* bb = body + (size_t)b * NFAC * RECF;

    unsigned fnd = 0u;   // bit k = voxel (ix,iy,iz0+k) found
    for (int w = 0; w < 8; ++w) {
        unsigned long long m = mp[w];   // wave-uniform -> SGPR
        while (m) {
            int bit = __builtin_ctzll(m);
            m &= m - 1;
            int f = __builtin_amdgcn_readfirstlane(w * 64 + bit);
            const float* bo = bb + f * RECF;
            float det = bo[0], v3x = bo[1], v3y = bo[2], v3z = bo[3];
            float A00 = bo[4],  A01 = bo[5],  A02 = bo[6];
            float A10 = bo[7],  A11 = bo[8],  A12 = bo[9];
            float A20 = bo[10], A21 = bo[11], A22 = bo[12];
            float margA = bo[13], dhi = bo[14], mhi = bo[15];
            float ss0 = bo[16], ss1 = bo[17], ss2 = bo[18], sss = bo[19];
            float dx = px - v3x, dy = py - v3y, dz0 = pz0 - v3z;
            // ref-exact at k=0 (left-assoc)
            float n0 = A00*dx + A01*dy + A02*dz0;
            float n1 = A10*dx + A11*dy + A12*dz0;
            float n2 = A20*dx + A21*dy + A22*dz0;
            float sm = n0 + n1 + n2;
            float nmargA = -margA;
#pragma unroll
            for (int k = 0; k < 4; ++k) {
                float mn = fminf(fminf(n0, n1), n2);   // v_min3_f32
                // definite: rigorously implies ref-inside (no divisions)
                bool def = (mn >= margA) & (sm <= dhi);
                // maybe: rigorously implied by ref-inside
                bool may = (mn >= nmargA) & (sm <= mhi);
                bool needex = may & !def & !((fnd >> k) & 1u);
                if (__any(needex)) {
                    // exact path: op-identical to reference (sign-folding
                    // commutes exactly through IEEE mul/add/div)
                    int izk = iz0 + k;
                    float pzk = (float)(2*izk + 1 - VWD) / 96.0f;
                    float dzk = pzk - v3z;
                    float e0 = A00*dx + A01*dy + A02*dzk;
                    float e1 = A10*dx + A11*dy + A12*dzk;
                    float e2 = A20*dx + A21*dy + A22*dzk;
                    float l0 = e0 / det;
                    float l1 = e1 / det;
                    float l2 = e2 / det;
                    float l3 = 1.0f - (l0 + l1 + l2);
                    bool inside = (l0 >= 0.0f) & (l0 <= 1.0f) &
                                  (l1 >= 0.0f) & (l1 <= 1.0f) &
                                  (l2 >= 0.0f) & (l2 <= 1.0f) &
                                  (l3 >= 0.0f) & (l3 <= 1.0f);
                    if (needex & inside) fnd |= (1u << k);
                }
                if (def) fnd |= (1u << k);
                if (k < 3) { n0 += ss0; n1 += ss1; n2 += ss2; sm += sss; }
            }
            if (__all(fnd == 15u)) goto done;
        }
    }
done:
    float4 v;
    v.x = (fnd & 1u) ? 1.0f : 0.0f;
    v.y = (fnd & 2u) ? 1.0f : 0.0f;
    v.z = (fnd & 4u) ? 1.0f : 0.0f;
    v.w = (fnd & 8u) ? 1.0f : 0.0f;
    *(float4*)&out[(size_t)b*(VWD*VWD*VWD) + (size_t)ix*(VWD*VWD) + iy*VWD + iz0] = v;
}

extern "C" void kernel_launch(void* const* d_in, const int* in_sizes, int n_in,
                              void* d_out, int out_size, void* d_ws, size_t ws_size,
                              hipStream_t stream) {
    const float* vertices = (const float*)d_in[0];   // (8, 2048, 3) f32
    const int*   facets   = (const int*)d_in[1];     // (8, 512, 4) int
    float*       out      = (float*)d_out;           // (8, 96, 96, 96) f32

    // d_ws layout: cul (384 KB) | body (320 KB) | masks (1.77 MB)
    float* cul  = (float*)d_ws;
    float* body = (float*)((char*)d_ws + (size_t)NBATCH * NFAC * CULF * 4);
    unsigned long long* msk =
        (unsigned long long*)((char*)d_ws + (size_t)NBATCH * NFAC * (CULF + RECF) * 4);

    precompute_kernel<<<NBATCH, 512, 0, stream>>>(vertices, facets, cul, body);
    mask_kernel<<<dim3(144, NBATCH), 512, 0, stream>>>(cul, msk);
    dim3 grid(NSLAB / 4, NBATCH);   // 864 blocks * 4 waves = 3456 slabs/batch
    voxelize_kernel<<<grid, 256, 0, stream>>>(body, msk, out);
}